// Round 1
// baseline (7635.072 us; speedup 1.0000x reference)
//
#include <hip/hip_runtime.h>
#include <hip/hip_bf16.h>
#include <math.h>

#define T_DIM 128
#define B_DIM 256
#define H_DIM 1024
#define N3    3072
#define KE    2048

typedef __attribute__((ext_vector_type(8))) short short8;
typedef __attribute__((ext_vector_type(4))) float float4v;
typedef __attribute__((ext_vector_type(4))) unsigned short ushort4v;

__device__ __forceinline__ unsigned short f2bf(float f) {
  union { float f; unsigned u; } v; v.f = f;
  unsigned u = v.u;
  unsigned r = u + 0x7FFFu + ((u >> 16) & 1u);  // round-to-nearest-even
  return (unsigned short)(r >> 16);
}

// Fragment-order offset for an A-operand (M x K) element (m, k), MFMA 16x16x32:
// lane l holds A[m = 16*mt + (l&15)][k = 32*kt + (l>>4)*8 + i], i = 0..7
// stored at ((mt*KT + kt)*64 + l)*8 + i   (KT = K/32)
__device__ __forceinline__ size_t afrag(int m, int k, int KT) {
  return ((((size_t)(m >> 4) * KT) + (k >> 5)) * 64
          + ((((k >> 3) & 3) << 4) | (m & 15))) * 8 + (k & 7);
}

__device__ __forceinline__ void store_bf4(unsigned short* p, const float* v) {
  ushort4v u;
  u.x = f2bf(v[0]); u.y = f2bf(v[1]); u.z = f2bf(v[2]); u.w = f2bf(v[3]);
  *(ushort4v*)p = u;
}

// ---------------- resets dtype detection ----------------
// If resets was pushed as int32, every value is 0 or 1. If pushed as 1-byte
// bool, reading the first 8192 ints (32 KB, within either allocation) will
// see packed values like 0x00010000 (>1) with probability ~1 at 5% density.
__global__ void detect_resets(const int* __restrict__ r, int* __restrict__ flag) {
  __shared__ int f;
  if (threadIdx.x == 0) f = 0;
  __syncthreads();
  int loc = 0;
  for (int i = threadIdx.x; i < 8192; i += 256) {
    unsigned v = (unsigned)r[i];
    if (v > 1u) loc = 1;
  }
  if (loc) f = 1;  // benign race
  __syncthreads();
  if (threadIdx.x == 0) *flag = f;
}

// ---------------- weight conversion to B-fragment order ----------------
// B-frag: lane l holds B[k = 32*kt + (l>>4)*8 + i][n = 16*nt + (l&15)],
// stored at ((nt*KT + kt)*64 + l)*8 + i
__global__ __launch_bounds__(256) void convert_w(const float* __restrict__ W,
                                                 unsigned short* __restrict__ Wsw,
                                                 int K, int N) {
  int nt = blockIdx.x;
  int kt = blockIdx.y;
  int KT = K >> 5;
  size_t base = ((size_t)nt * KT + kt) * 512;
  for (int e = threadIdx.x; e < 512; e += 256) {
    int i = e & 7;
    int l = (e >> 3) & 63;
    int k = (kt << 5) + ((l >> 4) << 3) + i;
    int n = (nt << 4) + (l & 15);
    Wsw[base + e] = f2bf(W[(size_t)k * N + n]);
  }
}

// ---------------- per-step: prepare e_t, mask state, err_mag ----------------
__global__ __launch_bounds__(256) void prepare_step(
    const float* __restrict__ a_all, const void* __restrict__ resets,
    const int* __restrict__ rflag,
    float* __restrict__ h, float* __restrict__ ahat,
    unsigned short* __restrict__ e_sw, unsigned short* __restrict__ h_sw,
    float* __restrict__ err_out, int t) {
  int b = blockIdx.x;
  int tid = threadIdx.x;
  int rv;
  if (*rflag) rv = (int)((const unsigned char*)resets)[t * B_DIM + b];
  else        rv = ((const int*)resets)[t * B_DIM + b];
  bool rst = (t == 0) || (rv != 0);

  const float* arow = a_all + ((size_t)t * B_DIM + b) * H_DIM;
  float* hrow = h + (size_t)b * H_DIM;
  float* prow = ahat + (size_t)b * H_DIM;

  int j0 = tid * 4;
  float pv[4], nv[4], hb[4];
  float sum_abs = 0.f;
#pragma unroll
  for (int jj = 0; jj < 4; ++jj) {
    int j = j0 + jj;
    float hv = rst ? 0.f : hrow[j];
    float av = rst ? 0.f : prow[j];
    if (rst) hrow[j] = 0.f;   // keep masked state for the gate update (z*h term)
    float d = arow[j] - av;
    float pos = fmaxf(d, 0.f);
    float neg = fmaxf(-d, 0.f);
    sum_abs += pos + neg;
    pv[jj] = pos; nv[jj] = neg; hb[jj] = hv;
  }
  store_bf4(e_sw + afrag(b, j0, KE >> 5), pv);
  store_bf4(e_sw + afrag(b, H_DIM + j0, KE >> 5), nv);
  store_bf4(h_sw + afrag(b, j0, H_DIM >> 5), hb);

  __shared__ float red[256];
  red[tid] = sum_abs;
  __syncthreads();
  for (int s = 128; s > 0; s >>= 1) {
    if (tid < s) red[tid] += red[tid + s];
    __syncthreads();
  }
  if (tid == 0) err_out[t * B_DIM + b] = red[0] * (1.0f / (float)H_DIM);
}

// ---------------- GEMM: C[M,N] = A[M,K] @ W[K,N] (+bias) (+relu) ----------------
// A_sw, W_sw in fragment order. Block = 4 waves; each wave owns one 16-row
// m-tile and a 64-column strip (4 n-tiles). Grid: (N/64, M/64).
__device__ __forceinline__ void gemm_body(
    const unsigned short* __restrict__ A_sw, const unsigned short* __restrict__ W_sw,
    const float* __restrict__ bias, float* __restrict__ C,
    int K, int N, bool relu) {
  int lane = threadIdx.x & 63;
  int wave = threadIdx.x >> 6;
  int mt = blockIdx.y * 4 + wave;
  int nt0 = blockIdx.x * 4;
  int KT = K >> 5;

  const short8* A8 = (const short8*)A_sw;
  const short8* W8 = (const short8*)W_sw;
  const short8* ap  = A8 + (size_t)mt * KT * 64 + lane;
  const short8* wp0 = W8 + (size_t)(nt0 + 0) * KT * 64 + lane;
  const short8* wp1 = W8 + (size_t)(nt0 + 1) * KT * 64 + lane;
  const short8* wp2 = W8 + (size_t)(nt0 + 2) * KT * 64 + lane;
  const short8* wp3 = W8 + (size_t)(nt0 + 3) * KT * 64 + lane;

  float4v acc[4];
#pragma unroll
  for (int j = 0; j < 4; ++j) acc[j] = (float4v){0.f, 0.f, 0.f, 0.f};

  for (int kt = 0; kt < KT; ++kt) {
    short8 a  = ap[(size_t)kt * 64];
    short8 b0 = wp0[(size_t)kt * 64];
    short8 b1 = wp1[(size_t)kt * 64];
    short8 b2 = wp2[(size_t)kt * 64];
    short8 b3 = wp3[(size_t)kt * 64];
    acc[0] = __builtin_amdgcn_mfma_f32_16x16x32_bf16(a, b0, acc[0], 0, 0, 0);
    acc[1] = __builtin_amdgcn_mfma_f32_16x16x32_bf16(a, b1, acc[1], 0, 0, 0);
    acc[2] = __builtin_amdgcn_mfma_f32_16x16x32_bf16(a, b2, acc[2], 0, 0, 0);
    acc[3] = __builtin_amdgcn_mfma_f32_16x16x32_bf16(a, b3, acc[3], 0, 0, 0);
  }

  // C/D layout (verified m89/m91): col = lane&15, row = (lane>>4)*4 + r
  int row0 = mt * 16 + ((lane >> 4) << 2);
  int cl = lane & 15;
#pragma unroll
  for (int j = 0; j < 4; ++j) {
    int col = (nt0 + j) * 16 + cl;
    float bv = bias ? bias[col] : 0.f;
#pragma unroll
    for (int r = 0; r < 4; ++r) {
      float v = acc[j][r] + bv;
      if (relu) v = fmaxf(v, 0.f);
      C[(size_t)(row0 + r) * N + col] = v;
    }
  }
}

__global__ __launch_bounds__(256) void gemm_gates(
    const unsigned short* __restrict__ e_sw, const unsigned short* __restrict__ Wi_sw,
    const float* __restrict__ b_i, float* __restrict__ gi,
    const unsigned short* __restrict__ h_sw, const unsigned short* __restrict__ Wh_sw,
    float* __restrict__ gh) {
  if (blockIdx.z == 0) gemm_body(e_sw, Wi_sw, b_i, gi, KE, N3, false);
  else                 gemm_body(h_sw, Wh_sw, nullptr, gh, H_DIM, N3, false);
}

__global__ __launch_bounds__(256) void gemm_pred(
    const unsigned short* __restrict__ hn_sw, const unsigned short* __restrict__ Wp_sw,
    const float* __restrict__ b_p, float* __restrict__ ahat) {
  gemm_body(hn_sw, Wp_sw, b_p, ahat, H_DIM, H_DIM, true);
}

// ---------------- per-step: gate nonlinearity + state update ----------------
__global__ __launch_bounds__(256) void gate_step(
    const float* __restrict__ gi, const float* __restrict__ gh,
    const float* __restrict__ b_hn,
    float* __restrict__ h, unsigned short* __restrict__ hn_sw,
    float* __restrict__ r_out, int t) {
  int b = blockIdx.x;
  int tid = threadIdx.x;
  const float* gir = gi + (size_t)b * N3;
  const float* ghr = gh + (size_t)b * N3;
  float* hrow = h + (size_t)b * H_DIM;
  float* orow = r_out + ((size_t)t * B_DIM + b) * H_DIM;

  int j0 = tid * 4;
  float nh4[4];
#pragma unroll
  for (int jj = 0; jj < 4; ++jj) {
    int j = j0 + jj;
    float ir = gir[j],          hr = ghr[j];
    float iz = gir[j + H_DIM],  hz = ghr[j + H_DIM];
    float in_ = gir[j + 2*H_DIM], hn_ = ghr[j + 2*H_DIM];
    float r = 1.f / (1.f + __expf(-(ir + hr)));
    float z = 1.f / (1.f + __expf(-(iz + hz)));
    float n = tanhf(in_ + r * (hn_ + b_hn[j]));
    float hv = hrow[j];
    float nh = (1.f - z) * n + z * hv;
    hrow[j] = nh;
    orow[j] = nh;
    nh4[jj] = nh;
  }
  store_bf4(hn_sw + afrag(b, j0, H_DIM >> 5), nh4);
}

// ---------------- launch ----------------
extern "C" void kernel_launch(void* const* d_in, const int* in_sizes, int n_in,
                              void* d_out, int out_size, void* d_ws, size_t ws_size,
                              hipStream_t stream) {
  (void)in_sizes; (void)n_in; (void)out_size; (void)ws_size;
  const float* a_all = (const float*)d_in[0];
  const void*  resets = d_in[1];
  const float* W_i  = (const float*)d_in[2];
  const float* b_i  = (const float*)d_in[3];
  const float* W_h  = (const float*)d_in[4];
  const float* b_hn = (const float*)d_in[5];
  const float* W_p  = (const float*)d_in[6];
  const float* b_p  = (const float*)d_in[7];

  float* out = (float*)d_out;
  float* r_out = out;
  float* err_out = out + (size_t)T_DIM * B_DIM * H_DIM;

  char* ws = (char*)d_ws;
  unsigned short* Wi_sw = (unsigned short*)ws; ws += (size_t)KE * N3 * 2;
  unsigned short* Wh_sw = (unsigned short*)ws; ws += (size_t)H_DIM * N3 * 2;
  unsigned short* Wp_sw = (unsigned short*)ws; ws += (size_t)H_DIM * H_DIM * 2;
  unsigned short* e_sw  = (unsigned short*)ws; ws += (size_t)B_DIM * KE * 2;
  unsigned short* h_sw  = (unsigned short*)ws; ws += (size_t)B_DIM * H_DIM * 2;
  unsigned short* hn_sw = (unsigned short*)ws; ws += (size_t)B_DIM * H_DIM * 2;
  float* h    = (float*)ws; ws += (size_t)B_DIM * H_DIM * 4;
  float* ahat = (float*)ws; ws += (size_t)B_DIM * H_DIM * 4;
  float* gi   = (float*)ws; ws += (size_t)B_DIM * N3 * 4;
  float* gh   = (float*)ws; ws += (size_t)B_DIM * N3 * 4;
  int* rflag  = (int*)ws;  ws += 256;

  detect_resets<<<1, 256, 0, stream>>>((const int*)resets, rflag);
  convert_w<<<dim3(N3 / 16, KE / 32), 256, 0, stream>>>(W_i, Wi_sw, KE, N3);
  convert_w<<<dim3(N3 / 16, H_DIM / 32), 256, 0, stream>>>(W_h, Wh_sw, H_DIM, N3);
  convert_w<<<dim3(H_DIM / 16, H_DIM / 32), 256, 0, stream>>>(W_p, Wp_sw, H_DIM, H_DIM);

  for (int t = 0; t < T_DIM; ++t) {
    prepare_step<<<B_DIM, 256, 0, stream>>>(a_all, resets, rflag, h, ahat,
                                            e_sw, h_sw, err_out, t);
    gemm_gates<<<dim3(N3 / 64, B_DIM / 64, 2), 256, 0, stream>>>(
        e_sw, Wi_sw, b_i, gi, h_sw, Wh_sw, gh);
    gate_step<<<B_DIM, 256, 0, stream>>>(gi, gh, b_hn, h, hn_sw, r_out, t);
    gemm_pred<<<dim3(H_DIM / 64, B_DIM / 64, 1), 256, 0, stream>>>(
        hn_sw, Wp_sw, b_p, ahat);
  }
}

// Round 2
// 4024.601 us; speedup vs baseline: 1.8971x; 1.8971x over previous
//
#include <hip/hip_runtime.h>
#include <hip/hip_bf16.h>
#include <math.h>

#define T_DIM 128
#define B_DIM 256
#define H_DIM 1024
#define N3    3072
#define KC    3072   // combined K for gates GEMM: 2048 (e) + 1024 (h)
#define KTC   96     // KC/32
#define KTP   32     // H_DIM/32

typedef __attribute__((ext_vector_type(8))) short short8;
typedef __attribute__((ext_vector_type(4))) float float4v;
typedef __attribute__((ext_vector_type(4))) unsigned short ushort4v;

__device__ __forceinline__ unsigned short f2bf(float f) {
  union { float f; unsigned u; } v; v.f = f;
  unsigned u = v.u;
  unsigned r = u + 0x7FFFu + ((u >> 16) & 1u);
  return (unsigned short)(r >> 16);
}

// A-fragment offset for MFMA 16x16x32: lane l holds A[m=16mt+(l&15)][k=32kt+(l>>4)*8+i]
// stored at ((mt*KT + kt)*64 + l)*8 + i
__device__ __forceinline__ size_t afrag(int m, int k, int KT) {
  return ((((size_t)(m >> 4) * KT) + (k >> 5)) * 64
          + ((((k >> 3) & 3) << 4) | (m & 15))) * 8 + (k & 7);
}

__device__ __forceinline__ void store_bf4(unsigned short* p, const float* v) {
  ushort4v u;
  u.x = f2bf(v[0]); u.y = f2bf(v[1]); u.z = f2bf(v[2]); u.w = f2bf(v[3]);
  *(ushort4v*)p = u;
}

__device__ __forceinline__ float sigm(float x) { return 1.f / (1.f + __expf(-x)); }

// ---------------- resets dtype detection + decode ----------------
__global__ void detect_resets(const int* __restrict__ r, int* __restrict__ flag) {
  __shared__ int f;
  if (threadIdx.x == 0) f = 0;
  __syncthreads();
  int loc = 0;
  for (int i = threadIdx.x; i < 8192; i += 256) {
    if ((unsigned)r[i] > 1u) loc = 1;
  }
  if (loc) f = 1;
  __syncthreads();
  if (threadIdx.x == 0) *flag = f;
}

__global__ __launch_bounds__(256) void decode_resets(
    const void* __restrict__ resets, const int* __restrict__ rflag,
    unsigned char* __restrict__ rb) {
  int t = blockIdx.x, b = threadIdx.x;
  int v;
  if (*rflag) v = (int)((const unsigned char*)resets)[t * B_DIM + b];
  else        v = ((const int*)resets)[t * B_DIM + b];
  rb[t * B_DIM + b] = (v != 0) ? 1 : 0;
}

// ---------------- weight conversion ----------------
// Gates weight buffer: virtual N = 64 jt * 4 groups * 16 cols. group g:
//   0 = r (Wi col j    | Wh col j),     1 = z (Wi col 1024+j | Wh col 1024+j)
//   2 = n_i (Wi col 2048+j, k<2048),    3 = n_h (Wh col 2048+j, k>=2048)
__global__ __launch_bounds__(256) void convert_gates(
    const float* __restrict__ Wi, const float* __restrict__ Wh,
    unsigned short* __restrict__ Wg) {
  int nt = blockIdx.x;   // 0..255
  int kt = blockIdx.y;   // 0..95
  int jt = nt >> 2, g = nt & 3;
  size_t base = ((size_t)nt * KTC + kt) * 512;
  for (int e = threadIdx.x; e < 512; e += 256) {
    int i = e & 7, l = (e >> 3) & 63;
    int k = (kt << 5) + ((l >> 4) << 3) + i;
    int j = (jt << 4) + (l & 15);
    float v = 0.f;
    if (g == 0) v = (k < 2048) ? Wi[(size_t)k * N3 + j] : Wh[(size_t)(k - 2048) * N3 + j];
    else if (g == 1) v = (k < 2048) ? Wi[(size_t)k * N3 + 1024 + j] : Wh[(size_t)(k - 2048) * N3 + 1024 + j];
    else if (g == 2) { if (k < 2048) v = Wi[(size_t)k * N3 + 2048 + j]; }
    else             { if (k >= 2048) v = Wh[(size_t)(k - 2048) * N3 + 2048 + j]; }
    Wg[base + e] = f2bf(v);
  }
}

__global__ __launch_bounds__(256) void convert_wp(const float* __restrict__ W,
                                                  unsigned short* __restrict__ Wsw) {
  int nt = blockIdx.x;   // 0..63
  int kt = blockIdx.y;   // 0..31
  size_t base = ((size_t)nt * KTP + kt) * 512;
  for (int e = threadIdx.x; e < 512; e += 256) {
    int i = e & 7, l = (e >> 3) & 63;
    int k = (kt << 5) + ((l >> 4) << 3) + i;
    int n = (nt << 4) + (l & 15);
    Wsw[base + e] = f2bf(W[(size_t)k * H_DIM + n]);
  }
}

// ---------------- init (t = 0 state) ----------------
__global__ __launch_bounds__(256) void init_state(
    const float* __restrict__ a_all,
    unsigned short* __restrict__ A0, float* __restrict__ h0,
    float* __restrict__ err_out) {
  int b = blockIdx.x, tid = threadIdx.x;
  int j0 = tid * 4;
  const float* arow = a_all + (size_t)b * H_DIM;
  float pv[4], nv[4], zz[4] = {0.f, 0.f, 0.f, 0.f};
  float s = 0.f;
#pragma unroll
  for (int jj = 0; jj < 4; ++jj) {
    float a = arow[j0 + jj];
    pv[jj] = fmaxf(a, 0.f);
    nv[jj] = fmaxf(-a, 0.f);
    s += pv[jj] + nv[jj];
    h0[(size_t)b * H_DIM + j0 + jj] = 0.f;
  }
  store_bf4(A0 + afrag(b, j0, KTC), pv);
  store_bf4(A0 + afrag(b, 1024 + j0, KTC), nv);
  store_bf4(A0 + afrag(b, 2048 + j0, KTC), zz);
  __shared__ float red[256];
  red[tid] = s;
  __syncthreads();
  for (int st = 128; st > 0; st >>= 1) {
    if (tid < st) red[tid] += red[tid + st];
    __syncthreads();
  }
  if (tid == 0) err_out[b] = red[0] * (1.0f / (float)H_DIM);
}

// ---------------- fused gates GEMM + GRU update ----------------
// grid (64 jt, 4 rowgroup), 256 threads. Wave w accumulates kt in [24w, 24w+24),
// LDS-reduce, epilogue computes r/z/n/new_h for 64 rows x 16 cols.
__global__ __launch_bounds__(256) void gates_fused(
    const unsigned short* __restrict__ A_sw, const unsigned short* __restrict__ Wg,
    const float* __restrict__ b_i, const float* __restrict__ b_hn,
    const float* __restrict__ h_in, float* __restrict__ h_out,
    unsigned short* __restrict__ A_next, unsigned short* __restrict__ hn_sw,
    const unsigned char* __restrict__ rb,
    float* __restrict__ r_out, int t) {
  int lane = threadIdx.x & 63, wave = threadIdx.x >> 6;
  int jt = blockIdx.x, rg = blockIdx.y;

  const short8* A8 = (const short8*)A_sw;
  const short8* B8 = (const short8*)Wg;

  float4v acc[4][4];
#pragma unroll
  for (int mi = 0; mi < 4; ++mi)
#pragma unroll
    for (int g = 0; g < 4; ++g) acc[mi][g] = (float4v){0.f, 0.f, 0.f, 0.f};

  int k0 = wave * 24, k1 = k0 + 24;
  int e1 = (k1 < 64) ? k1 : 64;
  int s2 = (k0 > 64) ? k0 : 64;

  // segment 1: e rows (kt < 64): r, z, n_i
#pragma unroll 2
  for (int kt = k0; kt < e1; ++kt) {
    short8 br = B8[((jt * 4 + 0) * KTC + kt) * 64 + lane];
    short8 bz = B8[((jt * 4 + 1) * KTC + kt) * 64 + lane];
    short8 bn = B8[((jt * 4 + 2) * KTC + kt) * 64 + lane];
#pragma unroll
    for (int mi = 0; mi < 4; ++mi) {
      short8 a = A8[((rg * 4 + mi) * KTC + kt) * 64 + lane];
      acc[mi][0] = __builtin_amdgcn_mfma_f32_16x16x32_bf16(a, br, acc[mi][0], 0, 0, 0);
      acc[mi][1] = __builtin_amdgcn_mfma_f32_16x16x32_bf16(a, bz, acc[mi][1], 0, 0, 0);
      acc[mi][2] = __builtin_amdgcn_mfma_f32_16x16x32_bf16(a, bn, acc[mi][2], 0, 0, 0);
    }
  }
  // segment 2: h rows (kt >= 64): r, z, n_h
#pragma unroll 2
  for (int kt = s2; kt < k1; ++kt) {
    short8 br = B8[((jt * 4 + 0) * KTC + kt) * 64 + lane];
    short8 bz = B8[((jt * 4 + 1) * KTC + kt) * 64 + lane];
    short8 bn = B8[((jt * 4 + 3) * KTC + kt) * 64 + lane];
#pragma unroll
    for (int mi = 0; mi < 4; ++mi) {
      short8 a = A8[((rg * 4 + mi) * KTC + kt) * 64 + lane];
      acc[mi][0] = __builtin_amdgcn_mfma_f32_16x16x32_bf16(a, br, acc[mi][0], 0, 0, 0);
      acc[mi][1] = __builtin_amdgcn_mfma_f32_16x16x32_bf16(a, bz, acc[mi][1], 0, 0, 0);
      acc[mi][3] = __builtin_amdgcn_mfma_f32_16x16x32_bf16(a, bn, acc[mi][3], 0, 0, 0);
    }
  }

  // cross-wave reduce (k-split partials)
  __shared__ float4v red[4][4][4][64];
#pragma unroll
  for (int mi = 0; mi < 4; ++mi)
#pragma unroll
    for (int g = 0; g < 4; ++g) red[wave][mi][g][lane] = acc[mi][g];
  __syncthreads();

  float4v accs[4];
#pragma unroll
  for (int g = 0; g < 4; ++g) {
    float4v s = red[0][wave][g][lane];
#pragma unroll
    for (int w = 1; w < 4; ++w) {
      float4v x = red[w][wave][g][lane];
      s[0] += x[0]; s[1] += x[1]; s[2] += x[2]; s[3] += x[3];
    }
    accs[g] = s;
  }

  // epilogue: wave handles m-tile == wave (16 rows x 16 cols)
  int col = lane & 15, q = lane >> 4;
  int j = jt * 16 + col;
  float br_ = b_i[j], bz_ = b_i[1024 + j], bn_ = b_i[2048 + j], bh = b_hn[j];
  int row_base = rg * 64 + wave * 16 + q * 4;
#pragma unroll
  for (int rr = 0; rr < 4; ++rr) {
    int row = row_base + rr;
    float r = sigm(accs[0][rr] + br_);
    float z = sigm(accs[1][rr] + bz_);
    float n = tanhf(accs[2][rr] + bn_ + r * (accs[3][rr] + bh));
    float hv = h_in[(size_t)row * H_DIM + j];
    float nh = (1.f - z) * n + z * hv;
    r_out[((size_t)t * B_DIM + row) * H_DIM + j] = nh;
    if (t < T_DIM - 1) {
      hn_sw[afrag(row, j, KTP)] = f2bf(nh);
      int rst = rb[(t + 1) * B_DIM + row];
      float hm = rst ? 0.f : nh;
      h_out[(size_t)row * H_DIM + j] = hm;
      A_next[afrag(row, 2048 + j, KTC)] = f2bf(hm);
    }
  }
}

// ---------------- fused pred GEMM + e_t / err for step t+1 ----------------
// grid (16 colgroup, 4 rowgroup), 256 threads. Wave w: kt in [8w, 8w+8).
__global__ __launch_bounds__(256) void pred_fused(
    const unsigned short* __restrict__ hn_sw, const unsigned short* __restrict__ Wp,
    const float* __restrict__ b_p, const float* __restrict__ a_all,
    const unsigned char* __restrict__ rb,
    unsigned short* __restrict__ A_next, float* __restrict__ err_out, int t) {
  int lane = threadIdx.x & 63, wave = threadIdx.x >> 6;
  int cg = blockIdx.x, rg = blockIdx.y;
  int nt0 = cg * 4;

  const short8* A8 = (const short8*)hn_sw;
  const short8* B8 = (const short8*)Wp;

  float4v acc[4][4];
#pragma unroll
  for (int mi = 0; mi < 4; ++mi)
#pragma unroll
    for (int n = 0; n < 4; ++n) acc[mi][n] = (float4v){0.f, 0.f, 0.f, 0.f};

  int k0 = wave * 8, k1 = k0 + 8;
#pragma unroll 2
  for (int kt = k0; kt < k1; ++kt) {
    short8 b0 = B8[((nt0 + 0) * KTP + kt) * 64 + lane];
    short8 b1 = B8[((nt0 + 1) * KTP + kt) * 64 + lane];
    short8 b2 = B8[((nt0 + 2) * KTP + kt) * 64 + lane];
    short8 b3 = B8[((nt0 + 3) * KTP + kt) * 64 + lane];
#pragma unroll
    for (int mi = 0; mi < 4; ++mi) {
      short8 a = A8[((rg * 4 + mi) * KTP + kt) * 64 + lane];
      acc[mi][0] = __builtin_amdgcn_mfma_f32_16x16x32_bf16(a, b0, acc[mi][0], 0, 0, 0);
      acc[mi][1] = __builtin_amdgcn_mfma_f32_16x16x32_bf16(a, b1, acc[mi][1], 0, 0, 0);
      acc[mi][2] = __builtin_amdgcn_mfma_f32_16x16x32_bf16(a, b2, acc[mi][2], 0, 0, 0);
      acc[mi][3] = __builtin_amdgcn_mfma_f32_16x16x32_bf16(a, b3, acc[mi][3], 0, 0, 0);
    }
  }

  __shared__ float4v red[4][4][4][64];
#pragma unroll
  for (int mi = 0; mi < 4; ++mi)
#pragma unroll
    for (int n = 0; n < 4; ++n) red[wave][mi][n][lane] = acc[mi][n];
  __syncthreads();

  float4v accs[4];
#pragma unroll
  for (int n = 0; n < 4; ++n) {
    float4v s = red[0][wave][n][lane];
#pragma unroll
    for (int w = 1; w < 4; ++w) {
      float4v x = red[w][wave][n][lane];
      s[0] += x[0]; s[1] += x[1]; s[2] += x[2]; s[3] += x[3];
    }
    accs[n] = s;
  }

  int cl = lane & 15, q = lane >> 4;
  int row_base = rg * 64 + wave * 16 + q * 4;
  float rsum[4] = {0.f, 0.f, 0.f, 0.f};
#pragma unroll
  for (int n = 0; n < 4; ++n) {
    int coln = (nt0 + n) * 16 + cl;
    float bp = b_p[coln];
#pragma unroll
    for (int rr = 0; rr < 4; ++rr) {
      int row = row_base + rr;
      float ah = fmaxf(accs[n][rr] + bp, 0.f);
      int rst = rb[(t + 1) * B_DIM + row];
      float am = rst ? 0.f : ah;
      float d = a_all[((size_t)(t + 1) * B_DIM + row) * H_DIM + coln] - am;
      float pos = fmaxf(d, 0.f), neg = fmaxf(-d, 0.f);
      A_next[afrag(row, coln, KTC)] = f2bf(pos);
      A_next[afrag(row, 1024 + coln, KTC)] = f2bf(neg);
      rsum[rr] += pos + neg;
    }
  }
  // reduce |d| over the 16 lanes that share rows (same q), then atomicAdd
#pragma unroll
  for (int rr = 0; rr < 4; ++rr) {
    float s = rsum[rr];
    s += __shfl_xor(s, 1);
    s += __shfl_xor(s, 2);
    s += __shfl_xor(s, 4);
    s += __shfl_xor(s, 8);
    if (cl == 0)
      atomicAdd(err_out + (size_t)(t + 1) * B_DIM + row_base + rr,
                s * (1.0f / (float)H_DIM));
  }
}

// ---------------- launch ----------------
extern "C" void kernel_launch(void* const* d_in, const int* in_sizes, int n_in,
                              void* d_out, int out_size, void* d_ws, size_t ws_size,
                              hipStream_t stream) {
  (void)in_sizes; (void)n_in; (void)out_size; (void)ws_size;
  const float* a_all = (const float*)d_in[0];
  const void*  resets = d_in[1];
  const float* W_i  = (const float*)d_in[2];
  const float* b_i  = (const float*)d_in[3];
  const float* W_h  = (const float*)d_in[4];
  const float* b_hn = (const float*)d_in[5];
  const float* W_p  = (const float*)d_in[6];
  const float* b_p  = (const float*)d_in[7];

  float* r_out = (float*)d_out;
  float* err_out = r_out + (size_t)T_DIM * B_DIM * H_DIM;

  char* ws = (char*)d_ws;
  unsigned short* Wg_sw = (unsigned short*)ws; ws += (size_t)256 * 16 * KC * 2;     // 25.2 MB
  unsigned short* Wp_sw = (unsigned short*)ws; ws += (size_t)H_DIM * H_DIM * 2;     // 2 MB
  unsigned short* A0    = (unsigned short*)ws; ws += (size_t)B_DIM * KC * 2;        // 1.5 MB
  unsigned short* A1    = (unsigned short*)ws; ws += (size_t)B_DIM * KC * 2;        // 1.5 MB
  unsigned short* hn_sw = (unsigned short*)ws; ws += (size_t)B_DIM * H_DIM * 2;     // 0.5 MB
  float* h0 = (float*)ws; ws += (size_t)B_DIM * H_DIM * 4;                          // 1 MB
  float* h1 = (float*)ws; ws += (size_t)B_DIM * H_DIM * 4;                          // 1 MB
  unsigned char* rb = (unsigned char*)ws; ws += T_DIM * B_DIM;                      // 32 KB
  int* rflag = (int*)ws; ws += 256;

  hipMemsetAsync(err_out, 0, (size_t)T_DIM * B_DIM * sizeof(float), stream);
  detect_resets<<<1, 256, 0, stream>>>((const int*)resets, rflag);
  decode_resets<<<T_DIM, 256, 0, stream>>>(resets, rflag, rb);
  convert_gates<<<dim3(256, KTC), 256, 0, stream>>>(W_i, W_h, Wg_sw);
  convert_wp<<<dim3(H_DIM / 16, KTP), 256, 0, stream>>>(W_p, Wp_sw);
  init_state<<<B_DIM, 256, 0, stream>>>(a_all, A0, h0, err_out);

  for (int t = 0; t < T_DIM; ++t) {
    const unsigned short* Acur = (t & 1) ? A1 : A0;
    unsigned short* Anext      = (t & 1) ? A0 : A1;
    const float* hcur = (t & 1) ? h1 : h0;
    float* hnext      = (t & 1) ? h0 : h1;
    gates_fused<<<dim3(64, 4), 256, 0, stream>>>(
        Acur, Wg_sw, b_i, b_hn, hcur, hnext, Anext, hn_sw, rb, r_out, t);
    if (t < T_DIM - 1)
      pred_fused<<<dim3(16, 4), 256, 0, stream>>>(
          hn_sw, Wp_sw, b_p, a_all, rb, Anext, err_out, t);
  }
}